// Round 1
// baseline (620.919 us; speedup 1.0000x reference)
//
#include <hip/hip_runtime.h>
#include <hip/hip_bf16.h>

#define B_  2
#define L_  2048
#define D_  2048
#define H_  16
#define DH_ 128

typedef __attribute__((ext_vector_type(8))) short bf16x8;
typedef __attribute__((ext_vector_type(4))) short short4v;
typedef __attribute__((ext_vector_type(4))) float f32x4;

__device__ __forceinline__ short f2bf(float f) {
  unsigned u = __float_as_uint(f);
  u = u + 0x7fffu + ((u >> 16) & 1u);   // round-to-nearest-even
  return (short)(u >> 16);
}
__device__ __forceinline__ float bf2f(short s) {
  return __uint_as_float(((unsigned)(unsigned short)s) << 16);
}

// ---------------- fp32 -> bf16 conversion (vectorized) ----------------
__global__ __launch_bounds__(256) void cvt_bf16_kernel(
    const float* __restrict__ in, short* __restrict__ out, int n4) {
  int i = blockIdx.x * 256 + threadIdx.x;
  if (i >= n4) return;
  float4 v = ((const float4*)in)[i];
  short4v o;
  o[0] = f2bf(v.x); o[1] = f2bf(v.y); o[2] = f2bf(v.z); o[3] = f2bf(v.w);
  ((short4v*)out)[i] = o;
}

// ---------------- RoPE cos/sin tables [L][64] ----------------
__global__ __launch_bounds__(256) void rope_table_kernel(
    float* __restrict__ cost, float* __restrict__ sint) {
  int idx = blockIdx.x * 256 + threadIdx.x;   // L*64 = 131072
  int l = idx >> 6, j = idx & 63;
  float inv = powf(10000.0f, -(float)(2 * j) * (1.0f / 128.0f));
  float ang = (float)l * inv;
  cost[idx] = cosf(ang);
  sint[idx] = sinf(ang);
}

// ---------------- GEMM C = A * B^T  (A:[M,K], B:[N,K], bf16 in, fp32 acc) ----------------
// m97 structure: 128x128 tile, 4 waves, BK=32, global_load_lds width 16.
template<bool BF16OUT>
__global__ __launch_bounds__(256) void gemm_bt_kernel(
    const short* __restrict__ A, const short* __restrict__ Bm,
    void* __restrict__ Cv, int M, int N, int K) {
  __shared__ short As[128 * 32];
  __shared__ short Bs[128 * 32];
  const int tm = blockIdx.x * 128;
  const int tn = blockIdx.y * 128;
  const int tid = threadIdx.x;
  const int w = tid >> 6, l = tid & 63;
  const int wm = (w >> 1) * 64, wn = (w & 1) * 64;
  const int lr = l & 15, lk = (l >> 4) * 8;

  f32x4 acc[4][4] = {};

  for (int k0 = 0; k0 < K; k0 += 32) {
#pragma unroll
    for (int c = 0; c < 2; ++c) {
      int chunk = w * 2 + c;               // 0..7, wave-uniform
      int elem = chunk * 512 + l * 8;      // element offset in 128x32 tile
      int row = elem >> 5, col = elem & 31;
      __builtin_amdgcn_global_load_lds(
          (const __attribute__((address_space(1))) void*)(A + (size_t)(tm + row) * K + k0 + col),
          (__attribute__((address_space(3))) void*)(As + chunk * 512), 16, 0, 0);
      __builtin_amdgcn_global_load_lds(
          (const __attribute__((address_space(1))) void*)(Bm + (size_t)(tn + row) * K + k0 + col),
          (__attribute__((address_space(3))) void*)(Bs + chunk * 512), 16, 0, 0);
    }
    __syncthreads();
    bf16x8 af[4], bfr[4];
#pragma unroll
    for (int i = 0; i < 4; ++i) af[i]  = *(const bf16x8*)&As[(wm + i * 16 + lr) * 32 + lk];
#pragma unroll
    for (int j = 0; j < 4; ++j) bfr[j] = *(const bf16x8*)&Bs[(wn + j * 16 + lr) * 32 + lk];
#pragma unroll
    for (int i = 0; i < 4; ++i)
#pragma unroll
      for (int j = 0; j < 4; ++j)
        acc[i][j] = __builtin_amdgcn_mfma_f32_16x16x32_bf16(af[i], bfr[j], acc[i][j], 0, 0, 0);
    __syncthreads();
  }

  const int r0 = (l >> 4) * 4;
#pragma unroll
  for (int i = 0; i < 4; ++i)
#pragma unroll
    for (int j = 0; j < 4; ++j)
#pragma unroll
      for (int r = 0; r < 4; ++r) {
        size_t idx = (size_t)(tm + wm + i * 16 + r0 + r) * N + (tn + wn + j * 16 + lr);
        if (BF16OUT) ((short*)Cv)[idx] = f2bf(acc[i][j][r]);
        else         ((float*)Cv)[idx] = acc[i][j][r];
      }
}

// ---------------- RoPE + pack to [B,H,L,DH] bf16 ----------------
__global__ __launch_bounds__(256) void rope_pack_kernel(
    const short* __restrict__ qkv, const float* __restrict__ cost,
    const float* __restrict__ sint, short* __restrict__ Qp,
    short* __restrict__ Kp, short* __restrict__ Vp) {
  int idx = blockIdx.x * 256 + threadIdx.x;   // B*L*H*DH = 8388608
  int dh = idx & 127;
  int h  = (idx >> 7) & 15;
  int l  = (idx >> 11) & 2047;
  int b  = idx >> 22;
  size_t src = (size_t)(b * L_ + l) * (3 * D_);
  int e = h * DH_ + dh;
  float q  = bf2f(qkv[src + e]);
  float k  = bf2f(qkv[src + D_ + e]);
  float qp = bf2f(qkv[src + (e ^ 64)]);       // rotate_half partner
  float kp = bf2f(qkv[src + D_ + (e ^ 64)]);
  int j = dh & 63;
  float c = cost[l * 64 + j], s = sint[l * 64 + j];
  float sgn = (dh < 64) ? -1.f : 1.f;
  size_t dst = ((size_t)(b * H_ + h) * L_ + l) * DH_ + dh;
  Qp[dst] = f2bf(q * c + sgn * qp * s);
  Kp[dst] = f2bf(k * c + sgn * kp * s);
  Vp[dst] = qkv[src + 2 * D_ + e];            // V: pass bits through
}

// ---------------- causal flash attention ----------------
// grid: (B*H, L/64). 4 waves x 16 q-rows. KV tiles of 32.
__global__ __launch_bounds__(256) void attn_kernel(
    const short* __restrict__ Qp, const short* __restrict__ Kp,
    const short* __restrict__ Vp, short* __restrict__ Out) {
  __shared__ short Ks[32 * 128];      // [k][d], XOR-swizzled
  __shared__ short Vt[128 * 32];      // [d][k]
  __shared__ short Plds[4][16 * 32];  // per-wave P tile [q][k]

  const int bh = blockIdx.x;
  const int q0 = blockIdx.y * 64;
  const int tid = threadIdx.x;
  const int w = tid >> 6, l = tid & 63;
  const int lr = l & 15, hi = l >> 4;
  const size_t base = (size_t)bh * (L_ * DH_);

  const int qrow = q0 + w * 16 + lr;
  bf16x8 qf[4];
#pragma unroll
  for (int s = 0; s < 4; ++s)
    qf[s] = *(const bf16x8*)&Qp[base + (size_t)qrow * DH_ + s * 32 + hi * 8];

  f32x4 o[8] = {};
  float mrow[4] = {-1e30f, -1e30f, -1e30f, -1e30f};
  float lsum[4] = {0.f, 0.f, 0.f, 0.f};
  const float scale = 0.08838834764831845f;  // 1/sqrt(128)

  const int ntiles = q0 / 32 + 2;
  for (int kt = 0; kt < ntiles; ++kt) {
    const int k0 = kt * 32;
    __syncthreads();   // prior tile fully consumed
    // stage K (swizzled) and V (transposed)
#pragma unroll
    for (int it = 0; it < 2; ++it) {
      int idx = (it * 256 + tid) * 8;   // element in 32x128 tile
      int row = idx >> 7, col = idx & 127;
      bf16x8 kv = *(const bf16x8*)&Kp[base + (size_t)(k0 + row) * DH_ + col];
      int off = (row * 256 + col * 2) ^ ((row & 7) << 4);
      *(bf16x8*)((char*)Ks + off) = kv;
      bf16x8 vv = *(const bf16x8*)&Vp[base + (size_t)(k0 + row) * DH_ + col];
#pragma unroll
      for (int jj = 0; jj < 8; ++jj)
        Vt[(col + jj) * 32 + row] = vv[jj];
    }
    __syncthreads();

    // S = Q K^T (scaled later)
    f32x4 sfr[2];
#pragma unroll
    for (int nf = 0; nf < 2; ++nf) {
      f32x4 acc = {};
      int krow = nf * 16 + lr;
#pragma unroll
      for (int st = 0; st < 4; ++st) {
        int off = (krow * 256 + (st * 32 + hi * 8) * 2) ^ ((krow & 7) << 4);
        bf16x8 kf = *(const bf16x8*)((char*)Ks + off);
        acc = __builtin_amdgcn_mfma_f32_16x16x32_bf16(qf[st], kf, acc, 0, 0, 0);
      }
      sfr[nf] = acc;
    }

    // scale + causal mask. lane holds rows hi*4+r, col k0+nf*16+lr
    const int qg = q0 + w * 16 + hi * 4;
#pragma unroll
    for (int nf = 0; nf < 2; ++nf) {
      int kg = k0 + nf * 16 + lr;
#pragma unroll
      for (int r = 0; r < 4; ++r) {
        float v = sfr[nf][r] * scale;
        sfr[nf][r] = (kg <= qg + r) ? v : -1e30f;
      }
    }
    // online softmax (fp32)
    float mt[4], rs[4], alpha[4];
#pragma unroll
    for (int r = 0; r < 4; ++r) mt[r] = fmaxf(sfr[0][r], sfr[1][r]);
#pragma unroll
    for (int dlt = 1; dlt < 16; dlt <<= 1)
#pragma unroll
      for (int r = 0; r < 4; ++r) mt[r] = fmaxf(mt[r], __shfl_xor(mt[r], dlt));
#pragma unroll
    for (int r = 0; r < 4; ++r) {
      float mn = fmaxf(mrow[r], mt[r]);
      alpha[r] = __expf(mrow[r] - mn);
      mrow[r] = mn;
      rs[r] = 0.f;
    }
#pragma unroll
    for (int nf = 0; nf < 2; ++nf)
#pragma unroll
      for (int r = 0; r < 4; ++r) {
        float p = __expf(sfr[nf][r] - mrow[r]);
        sfr[nf][r] = p;
        rs[r] += p;
      }
#pragma unroll
    for (int dlt = 1; dlt < 16; dlt <<= 1)
#pragma unroll
      for (int r = 0; r < 4; ++r) rs[r] += __shfl_xor(rs[r], dlt);
#pragma unroll
    for (int r = 0; r < 4; ++r) lsum[r] = lsum[r] * alpha[r] + rs[r];
#pragma unroll
    for (int f = 0; f < 8; ++f)
#pragma unroll
      for (int r = 0; r < 4; ++r) o[f][r] *= alpha[r];

    // P -> bf16 -> LDS (D-layout -> A-layout transpose)
#pragma unroll
    for (int nf = 0; nf < 2; ++nf)
#pragma unroll
      for (int r = 0; r < 4; ++r)
        Plds[w][(hi * 4 + r) * 32 + nf * 16 + lr] = f2bf(sfr[nf][r]);
    __syncthreads();

    // O += P V
    bf16x8 pf = *(const bf16x8*)&Plds[w][lr * 32 + hi * 8];
#pragma unroll
    for (int f = 0; f < 8; ++f) {
      bf16x8 vf = *(const bf16x8*)&Vt[(f * 16 + lr) * 32 + hi * 8];
      o[f] = __builtin_amdgcn_mfma_f32_16x16x32_bf16(pf, vf, o[f], 0, 0, 0);
    }
  }

  // epilogue: divide by l, write [B, L, H*DH] bf16
  const int b = bh >> 4, h = bh & 15;
#pragma unroll
  for (int f = 0; f < 8; ++f)
#pragma unroll
    for (int r = 0; r < 4; ++r) {
      int qg2 = q0 + w * 16 + hi * 4 + r;
      float v = o[f][r] / lsum[r];
      Out[((size_t)b * L_ + qg2) * D_ + h * DH_ + f * 16 + lr] = f2bf(v);
    }
}

// ---------------- launcher ----------------
extern "C" void kernel_launch(void* const* d_in, const int* in_sizes, int n_in,
                              void* d_out, int out_size, void* d_ws, size_t ws_size,
                              hipStream_t stream) {
  const float* x     = (const float*)d_in[0];
  const float* w_qkv = (const float*)d_in[1];
  const float* w_out = (const float*)d_in[2];
  float* out = (float*)d_out;

  char* ws = (char*)d_ws;
  size_t off = 0;
  auto alloc = [&](size_t bytes) -> char* {
    char* p = ws + off;
    off += (bytes + 255) & ~(size_t)255;
    return p;
  };
  const size_t nX = (size_t)B_ * L_ * D_;          // 8388608
  const size_t nWqkv = (size_t)3 * D_ * D_;        // 12582912
  const size_t nWout = (size_t)D_ * D_;            // 4194304
  short* xb    = (short*)alloc(nX * 2);
  short* wqkvb = (short*)alloc(nWqkv * 2);
  short* woutb = (short*)alloc(nWout * 2);
  short* qkvb  = (short*)alloc((size_t)B_ * L_ * 3 * D_ * 2);
  short* Qp    = (short*)alloc(nX * 2);
  short* Kp    = (short*)alloc(nX * 2);
  short* Vp    = (short*)alloc(nX * 2);
  short* attnb = (short*)alloc(nX * 2);
  float* cost  = (float*)alloc((size_t)L_ * 64 * 4);
  float* sint  = (float*)alloc((size_t)L_ * 64 * 4);

  // 1. convert inputs to bf16
  cvt_bf16_kernel<<<(int)(nX / 1024), 256, 0, stream>>>(x, xb, (int)(nX / 4));
  cvt_bf16_kernel<<<(int)(nWqkv / 1024), 256, 0, stream>>>(w_qkv, wqkvb, (int)(nWqkv / 4));
  cvt_bf16_kernel<<<(int)(nWout / 1024), 256, 0, stream>>>(w_out, woutb, (int)(nWout / 4));
  // 2. rope tables
  rope_table_kernel<<<(L_ * 64) / 256, 256, 0, stream>>>(cost, sint);
  // 3. qkv = x @ w_qkv^T   [4096, 6144] bf16
  gemm_bt_kernel<true><<<dim3(32, 48), 256, 0, stream>>>(xb, wqkvb, (void*)qkvb,
                                                         B_ * L_, 3 * D_, D_);
  // 4. rope + pack
  rope_pack_kernel<<<(int)(nX / 256), 256, 0, stream>>>(qkvb, cost, sint, Qp, Kp, Vp);
  // 5. attention
  attn_kernel<<<dim3(B_ * H_, L_ / 64), 256, 0, stream>>>(Qp, Kp, Vp, attnb);
  // 6. out = attn @ w_out^T  [4096, 2048] fp32
  gemm_bt_kernel<false><<<dim3(32, 16), 256, 0, stream>>>(attnb, woutb, (void*)out,
                                                          B_ * L_, D_, D_);
}

// Round 3
// 448.506 us; speedup vs baseline: 1.3844x; 1.3844x over previous
//
#include <hip/hip_runtime.h>
#include <hip/hip_bf16.h>

#define B_  2
#define L_  2048
#define D_  2048
#define H_  16
#define DH_ 128

typedef __attribute__((ext_vector_type(8))) short bf16x8;
typedef __attribute__((ext_vector_type(4))) short short4v;
typedef __attribute__((ext_vector_type(4))) float f32x4;
typedef __attribute__((ext_vector_type(16))) float f32x16;

__device__ __forceinline__ short f2bf(float f) {
  unsigned u = __float_as_uint(f);
  u = u + 0x7fffu + ((u >> 16) & 1u);   // round-to-nearest-even
  return (short)(u >> 16);
}
__device__ __forceinline__ float bf2f(short s) {
  return __uint_as_float(((unsigned)(unsigned short)s) << 16);
}
__device__ __forceinline__ int pkbf(float a, float b) {
  return (int)(unsigned short)f2bf(a) | (((int)(unsigned short)f2bf(b)) << 16);
}

// ---------------- fp32 -> bf16 conversion (vectorized) ----------------
__global__ __launch_bounds__(256) void cvt_bf16_kernel(
    const float* __restrict__ in, short* __restrict__ out, int n4) {
  int i = blockIdx.x * 256 + threadIdx.x;
  if (i >= n4) return;
  float4 v = ((const float4*)in)[i];
  short4v o;
  o[0] = f2bf(v.x); o[1] = f2bf(v.y); o[2] = f2bf(v.z); o[3] = f2bf(v.w);
  ((short4v*)out)[i] = o;
}

// ---------------- RoPE cos/sin tables [L][64] ----------------
__global__ __launch_bounds__(256) void rope_table_kernel(
    float* __restrict__ cost, float* __restrict__ sint) {
  int idx = blockIdx.x * 256 + threadIdx.x;   // L*64 = 131072
  int l = idx >> 6, j = idx & 63;
  float inv = powf(10000.0f, -(float)(2 * j) * (1.0f / 128.0f));
  float ang = (float)l * inv;
  cost[idx] = cosf(ang);
  sint[idx] = sinf(ang);
}

// ---------------- GEMM C = A * B^T  (A:[M,K], B:[N,K], bf16 in, fp32 acc) ----------------
template<bool BF16OUT>
__global__ __launch_bounds__(256) void gemm_bt_kernel(
    const short* __restrict__ A, const short* __restrict__ Bm,
    void* __restrict__ Cv, int M, int N, int K) {
  __shared__ short As[128 * 32];
  __shared__ short Bs[128 * 32];
  const int tm = blockIdx.x * 128;
  const int tn = blockIdx.y * 128;
  const int tid = threadIdx.x;
  const int w = tid >> 6, l = tid & 63;
  const int wm = (w >> 1) * 64, wn = (w & 1) * 64;
  const int lr = l & 15, lk = (l >> 4) * 8;

  f32x4 acc[4][4] = {};

  for (int k0 = 0; k0 < K; k0 += 32) {
#pragma unroll
    for (int c = 0; c < 2; ++c) {
      int chunk = w * 2 + c;               // 0..7, wave-uniform
      int elem = chunk * 512 + l * 8;      // element offset in 128x32 tile
      int row = elem >> 5, col = elem & 31;
      __builtin_amdgcn_global_load_lds(
          (const __attribute__((address_space(1))) void*)(A + (size_t)(tm + row) * K + k0 + col),
          (__attribute__((address_space(3))) void*)(As + chunk * 512), 16, 0, 0);
      __builtin_amdgcn_global_load_lds(
          (const __attribute__((address_space(1))) void*)(Bm + (size_t)(tn + row) * K + k0 + col),
          (__attribute__((address_space(3))) void*)(Bs + chunk * 512), 16, 0, 0);
    }
    __syncthreads();
    bf16x8 af[4], bfr[4];
#pragma unroll
    for (int i = 0; i < 4; ++i) af[i]  = *(const bf16x8*)&As[(wm + i * 16 + lr) * 32 + lk];
#pragma unroll
    for (int j = 0; j < 4; ++j) bfr[j] = *(const bf16x8*)&Bs[(wn + j * 16 + lr) * 32 + lk];
#pragma unroll
    for (int i = 0; i < 4; ++i)
#pragma unroll
      for (int j = 0; j < 4; ++j)
        acc[i][j] = __builtin_amdgcn_mfma_f32_16x16x32_bf16(af[i], bfr[j], acc[i][j], 0, 0, 0);
    __syncthreads();
  }

  const int r0 = (l >> 4) * 4;
#pragma unroll
  for (int i = 0; i < 4; ++i)
#pragma unroll
    for (int j = 0; j < 4; ++j)
#pragma unroll
      for (int r = 0; r < 4; ++r) {
        size_t idx = (size_t)(tm + wm + i * 16 + r0 + r) * N + (tn + wn + j * 16 + lr);
        if (BF16OUT) ((short*)Cv)[idx] = f2bf(acc[i][j][r]);
        else         ((float*)Cv)[idx] = acc[i][j][r];
      }
}

// ---------------- RoPE + pack Q (scaled) and K to [B,H,L,DH] bf16 ----------------
__global__ __launch_bounds__(256) void rope_pack_kernel(
    const short* __restrict__ qkv, const float* __restrict__ cost,
    const float* __restrict__ sint, short* __restrict__ Qp,
    short* __restrict__ Kp) {
  int idx = blockIdx.x * 256 + threadIdx.x;   // B*L*H*64 = 4194304
  int dh = idx & 63;
  int h  = (idx >> 6) & 15;
  int l  = (idx >> 10) & 2047;
  int b  = idx >> 21;
  size_t src = (size_t)(b * L_ + l) * (3 * D_);
  int e = h * DH_ + dh;
  float c = cost[l * 64 + dh], s = sint[l * 64 + dh];
  float q1 = bf2f(qkv[src + e]),        q2 = bf2f(qkv[src + e + 64]);
  float k1 = bf2f(qkv[src + D_ + e]),   k2 = bf2f(qkv[src + D_ + e + 64]);
  const float scale = 0.08838834764831845f;   // 1/sqrt(128), folded into Q
  size_t dst = ((size_t)(b * H_ + h) * L_ + l) * DH_ + dh;
  Qp[dst]      = f2bf((q1 * c - q2 * s) * scale);
  Qp[dst + 64] = f2bf((q2 * c + q1 * s) * scale);
  Kp[dst]      = f2bf(k1 * c - k2 * s);
  Kp[dst + 64] = f2bf(k2 * c + k1 * s);
}

// ---------------- V transpose: qkv V-part [b,l,h,d] -> VtG [b,h,d,l] ----------------
// diagonal-LDS 64x64 tile transpose (conflict-free scalar writes/reads)
__global__ __launch_bounds__(256) void transpose_v_kernel(
    const short* __restrict__ qkv, short* __restrict__ VtG) {
  __shared__ short T[64 * 64];
  int bid = blockIdx.x;              // 32(lt) x 2(dt) x 32(bh) = 2048
  int lt = bid & 31, dt = (bid >> 5) & 1, bh = bid >> 6;
  int b = bh >> 4, h = bh & 15;
  int l0 = lt * 64, d0 = dt * 64;
  int tid = threadIdx.x;
#pragma unroll
  for (int it = 0; it < 2; ++it) {
    int row = it * 32 + (tid >> 3);      // local l
    int c   = (tid & 7) * 8;             // local d chunk
    bf16x8 v = *(const bf16x8*)&qkv[(size_t)(b * L_ + l0 + row) * (3 * D_) + 2 * D_ + h * DH_ + d0 + c];
#pragma unroll
    for (int jj = 0; jj < 8; ++jj)
      T[row * 64 + ((c + jj + row) & 63)] = v[jj];
  }
  __syncthreads();
  int d = tid >> 2, lc = (tid & 3) * 16;
  short tmp[16];
#pragma unroll
  for (int j = 0; j < 16; ++j)
    tmp[j] = T[(lc + j) * 64 + ((d + lc + j) & 63)];
  size_t obase = (size_t)(bh * DH_ + d0 + d) * L_ + l0 + lc;
  *(bf16x8*)&VtG[obase]     = *(bf16x8*)&tmp[0];
  *(bf16x8*)&VtG[obase + 8] = *(bf16x8*)&tmp[8];
}

// ---------------- causal flash attention ----------------
// 512 blocks (XCD-grouped), 4 waves x 32 q-rows = 128 q/block, KVBLK=64.
// 32x32x16 MFMA, swapped QK^T (S^T), in-register P exchange, dbuf staging.
__global__ __launch_bounds__(256) void attn_kernel(
    const short* __restrict__ Qp, const short* __restrict__ Kp,
    const short* __restrict__ VtG, short* __restrict__ Out) {
  __shared__ short lds[2][16384];    // per buf: K 64x128 (8192) + Vt 128x64 (8192), XOR-swizzled

  const int f   = blockIdx.x;        // 0..511
  const int bh  = (f & 7) + 8 * (f >> 7);
  const int qt  = (f >> 3) & 15;
  const int q0  = qt * 128;
  const int tid = threadIdx.x;
  const int w = tid >> 6, l = tid & 63;
  const int lq = l & 31, hi = l >> 5;
  const int qw = q0 + w * 32;
  const int b = bh >> 4, h = bh & 15;
  const size_t kqbase = (size_t)bh * (L_ * DH_);

  // Q fragments (B-operand of swapped QK^T): lane owns q = qw+lq, all 128 d
  bf16x8 qf[8];
#pragma unroll
  for (int st = 0; st < 8; ++st)
    qf[st] = *(const bf16x8*)&Qp[kqbase + (size_t)(qw + lq) * DH_ + st * 16 + hi * 8];

  f32x16 oacc[4];
#pragma unroll
  for (int dm = 0; dm < 4; ++dm)
#pragma unroll
    for (int r = 0; r < 16; ++r) oacc[dm][r] = 0.f;
  float m_run = -1e30f, l_run = 0.f;

  const int nt = qt * 2 + 2;

  auto stage = [&](int bf, int kt) {
    int k0 = kt * 64;
#pragma unroll
    for (int i = 0; i < 4; ++i) {
      int c = w * 4 + i;
      int X = c * 1024 + l * 16;
      {  // K region: 64 rows x 256 B, row-bit XOR swizzled source
        int row = X >> 8, bcol = (X & 255) ^ ((row & 7) << 4);
        __builtin_amdgcn_global_load_lds(
            (const __attribute__((address_space(1))) void*)(Kp + kqbase + (size_t)(k0 + row) * DH_ + (bcol >> 1)),
            (__attribute__((address_space(3))) void*)(&lds[bf][c * 512]), 16, 0, 0);
      }
      {  // Vt region: 128 rows x 128 B
        int row = X >> 7, bcol = (X & 127) ^ ((row & 7) << 4);
        __builtin_amdgcn_global_load_lds(
            (const __attribute__((address_space(1))) void*)(VtG + (size_t)(bh * DH_ + row) * L_ + k0 + (bcol >> 1)),
            (__attribute__((address_space(3))) void*)(&lds[bf][8192 + c * 512]), 16, 0, 0);
      }
    }
  };

  auto compute = [&](int bf, int kt) {
    int k0 = kt * 64;
    if (k0 > qw + 31) return;          // wave fully above diagonal: skip
    const char* ksB = (const char*)&lds[bf][0];
    const char* vsB = (const char*)&lds[bf][8192];

    // S^T = K . Q^T   (2 frags of 32k x 32q, contraction over d=128)
    f32x16 sacc[2];
#pragma unroll
    for (int fm = 0; fm < 2; ++fm)
#pragma unroll
      for (int r = 0; r < 16; ++r) sacc[fm][r] = 0.f;
#pragma unroll
    for (int st = 0; st < 8; ++st) {
#pragma unroll
      for (int fm = 0; fm < 2; ++fm) {
        int krow = fm * 32 + lq;
        int byte = (krow << 8) + ((st * 32 + hi * 16) ^ ((krow & 7) << 4));
        bf16x8 kf = *(const bf16x8*)(ksB + byte);
        sacc[fm] = __builtin_amdgcn_mfma_f32_32x32x16_bf16(kf, qf[st], sacc[fm], 0, 0, 0);
      }
    }

    // causal mask (only on diagonal-crossing tiles; k = k0+fm*32+(r&3)+8*(r>>2)+4*hi, q = qw+lq)
    if (k0 + 63 > qw) {
      int q = qw + lq;
#pragma unroll
      for (int fm = 0; fm < 2; ++fm)
#pragma unroll
        for (int r = 0; r < 16; ++r) {
          int k = k0 + fm * 32 + (r & 3) + 8 * (r >> 2) + 4 * hi;
          if (k > q) sacc[fm][r] = -1e30f;
        }
    }

    // online softmax: lane-local over 32 k + combine with partner lane (l^32, same q)
    float pmax = sacc[0][0];
#pragma unroll
    for (int fm = 0; fm < 2; ++fm)
#pragma unroll
      for (int r = 0; r < 16; ++r) pmax = fmaxf(pmax, sacc[fm][r]);
    pmax = fmaxf(pmax, __shfl_xor(pmax, 32));
    float mnew = fmaxf(m_run, pmax);
    float alpha = __expf(m_run - mnew);
    m_run = mnew;
    float rsum = 0.f;
#pragma unroll
    for (int fm = 0; fm < 2; ++fm)
#pragma unroll
      for (int r = 0; r < 16; ++r) {
        float e = __expf(sacc[fm][r] - mnew);
        sacc[fm][r] = e;
        rsum += e;
      }
    rsum += __shfl_xor(rsum, 32);
    l_run = l_run * alpha + rsum;
#pragma unroll
    for (int dm = 0; dm < 4; ++dm)
#pragma unroll
      for (int r = 0; r < 16; ++r) oacc[dm][r] *= alpha;

    // P -> bf16 packed dwords (pb[fm*8+i] = {p[2i], p[2i+1]})
    int pb[16];
#pragma unroll
    for (int fm = 0; fm < 2; ++fm)
#pragma unroll
      for (int i2 = 0; i2 < 8; ++i2)
        pb[fm * 8 + i2] = pkbf(sacc[fm][2 * i2], sacc[fm][2 * i2 + 1]);

    // O^T += V^T . P^T : per 16-k slice, build P-frag via shfl_xor(32)+select
#pragma unroll
    for (int kk = 0; kk < 4; ++kk) {
      int idx0 = (kk >> 1) * 8 + (kk & 1) * 4;
      int sw0 = __shfl_xor(pb[idx0],     32);
      int sw1 = __shfl_xor(pb[idx0 + 1], 32);
      int sw2 = __shfl_xor(pb[idx0 + 2], 32);
      int sw3 = __shfl_xor(pb[idx0 + 3], 32);
      union { int i[4]; bf16x8 v; } u;
      u.i[0] = hi ? sw2 : pb[idx0];
      u.i[1] = hi ? sw3 : pb[idx0 + 1];
      u.i[2] = hi ? pb[idx0 + 2] : sw0;
      u.i[3] = hi ? pb[idx0 + 3] : sw1;
#pragma unroll
      for (int dm = 0; dm < 4; ++dm) {
        int vrow = dm * 32 + lq;
        int byte = (vrow << 7) + ((kk * 32 + hi * 16) ^ ((vrow & 7) << 4));
        bf16x8 vf = *(const bf16x8*)(vsB + byte);
        oacc[dm] = __builtin_amdgcn_mfma_f32_32x32x16_bf16(vf, u.v, oacc[dm], 0, 0, 0);
      }
    }
  };

  stage(0, 0);
  __syncthreads();
  for (int kt = 0; kt < nt; ++kt) {
    if (kt + 1 < nt) stage((kt + 1) & 1, kt + 1);
    compute(kt & 1, kt);
    __syncthreads();
  }

  // epilogue: O^T[d][q] / l_run -> Out[b, q, h*128+d] bf16
  float inv = 1.0f / l_run;
  int q = qw + lq;
  size_t rowbase = ((size_t)(b * L_ + q)) * D_ + h * DH_;
#pragma unroll
  for (int dm = 0; dm < 4; ++dm)
#pragma unroll
    for (int g = 0; g < 4; ++g) {
      short4v s4;
#pragma unroll
      for (int t = 0; t < 4; ++t) s4[t] = f2bf(oacc[dm][4 * g + t] * inv);
      *(short4v*)&Out[rowbase + dm * 32 + 8 * g + 4 * hi] = s4;
    }
}

// ---------------- launcher ----------------
extern "C" void kernel_launch(void* const* d_in, const int* in_sizes, int n_in,
                              void* d_out, int out_size, void* d_ws, size_t ws_size,
                              hipStream_t stream) {
  const float* x     = (const float*)d_in[0];
  const float* w_qkv = (const float*)d_in[1];
  const float* w_out = (const float*)d_in[2];
  float* out = (float*)d_out;

  char* ws = (char*)d_ws;
  size_t off = 0;
  auto alloc = [&](size_t bytes) -> char* {
    char* p = ws + off;
    off += (bytes + 255) & ~(size_t)255;
    return p;
  };
  const size_t nX = (size_t)B_ * L_ * D_;          // 8388608
  const size_t nWqkv = (size_t)3 * D_ * D_;        // 12582912
  const size_t nWout = (size_t)D_ * D_;            // 4194304
  short* xb    = (short*)alloc(nX * 2);
  short* wqkvb = (short*)alloc(nWqkv * 2);
  short* woutb = (short*)alloc(nWout * 2);
  short* qkvb  = (short*)alloc((size_t)B_ * L_ * 3 * D_ * 2);
  short* Qp    = (short*)alloc(nX * 2);
  short* Kp    = (short*)alloc(nX * 2);
  short* VtG   = (short*)alloc(nX * 2);
  short* attnb = (short*)alloc(nX * 2);
  float* cost  = (float*)alloc((size_t)L_ * 64 * 4);
  float* sint  = (float*)alloc((size_t)L_ * 64 * 4);

  // 1. convert inputs to bf16
  cvt_bf16_kernel<<<(int)(nX / 1024), 256, 0, stream>>>(x, xb, (int)(nX / 4));
  cvt_bf16_kernel<<<(int)(nWqkv / 1024), 256, 0, stream>>>(w_qkv, wqkvb, (int)(nWqkv / 4));
  cvt_bf16_kernel<<<(int)(nWout / 1024), 256, 0, stream>>>(w_out, woutb, (int)(nWout / 4));
  // 2. rope tables
  rope_table_kernel<<<(L_ * 64) / 256, 256, 0, stream>>>(cost, sint);
  // 3. qkv = x @ w_qkv^T   [4096, 6144] bf16
  gemm_bt_kernel<true><<<dim3(32, 48), 256, 0, stream>>>(xb, wqkvb, (void*)qkvb,
                                                         B_ * L_, 3 * D_, D_);
  // 4. rope + pack Q,K ; transpose V
  rope_pack_kernel<<<(int)(nX / 512), 256, 0, stream>>>(qkvb, cost, sint, Qp, Kp);
  transpose_v_kernel<<<2048, 256, 0, stream>>>(qkvb, VtG);
  // 5. attention
  attn_kernel<<<512, 256, 0, stream>>>(Qp, Kp, VtG, attnb);
  // 6. out = attn @ w_out^T  [4096, 2048] fp32
  gemm_bt_kernel<false><<<dim3(32, 16), 256, 0, stream>>>(attnb, woutb, (void*)out,
                                                          B_ * L_, D_, D_);
}

// Round 4
// 395.942 us; speedup vs baseline: 1.5682x; 1.1328x over previous
//
#include <hip/hip_runtime.h>
#include <hip/hip_bf16.h>

#define B_  2
#define L_  2048
#define D_  2048
#define H_  16
#define DH_ 128

typedef __attribute__((ext_vector_type(8))) short bf16x8;
typedef __attribute__((ext_vector_type(4))) short short4v;
typedef __attribute__((ext_vector_type(4))) float f32x4;
typedef __attribute__((ext_vector_type(16))) float f32x16;

__device__ __forceinline__ short f2bf(float f) {
  unsigned u = __float_as_uint(f);
  u = u + 0x7fffu + ((u >> 16) & 1u);   // round-to-nearest-even
  return (short)(u >> 16);
}
__device__ __forceinline__ float bf2f(short s) {
  return __uint_as_float(((unsigned)(unsigned short)s) << 16);
}
__device__ __forceinline__ int pkbf(float a, float b) {
  return (int)(unsigned short)f2bf(a) | (((int)(unsigned short)f2bf(b)) << 16);
}

// ---------------- fp32 -> bf16 conversion (vectorized) ----------------
__global__ __launch_bounds__(256) void cvt_bf16_kernel(
    const float* __restrict__ in, short* __restrict__ out, int n4) {
  int i = blockIdx.x * 256 + threadIdx.x;
  if (i >= n4) return;
  float4 v = ((const float4*)in)[i];
  short4v o;
  o[0] = f2bf(v.x); o[1] = f2bf(v.y); o[2] = f2bf(v.z); o[3] = f2bf(v.w);
  ((short4v*)out)[i] = o;
}

// ---------------- RoPE cos/sin tables [L][64] ----------------
__global__ __launch_bounds__(256) void rope_table_kernel(
    float* __restrict__ cost, float* __restrict__ sint) {
  int idx = blockIdx.x * 256 + threadIdx.x;   // L*64 = 131072
  int l = idx >> 6, j = idx & 63;
  float inv = powf(10000.0f, -(float)(2 * j) * (1.0f / 128.0f));
  float ang = (float)l * inv;
  cost[idx] = cosf(ang);
  sint[idx] = sinf(ang);
}

// ---------------- GEMM C = A * B^T  (T2+T3+T4+T5 stack) ----------------
// BM=256, BN=128, BK=64. 8 waves (4M x 2N), 512 threads. 3 LDS buffers
// (144 KB): counted vmcnt(6) at tile boundary -- loads for tile j+2 issued
// during tile j, tile j+1's 6 loads stay in flight across the barrier.
// Swizzle: LDS linear dest for global_load_lds, inverse-swizzled global
// source, ds_read at byte ^ ((row&7)<<4)  (rule 21, both-sides).
template<bool BF16OUT>
__global__ __launch_bounds__(512, 2) void gemm256_kernel(
    const short* __restrict__ A, const short* __restrict__ Bm,
    void* __restrict__ Cv, int M, int N, int K, int nbn) {
  __shared__ short lds[3][24576];    // per buf: A 256x64 (32KB) + B 128x64 (16KB)
  const int NT = K >> 6;
  const int tid = threadIdx.x;
  const int w = tid >> 6, l = tid & 63;
  const int wrm = w >> 1, wnn = w & 1;
  const int lr = l & 15, c4 = l >> 4;

  // bijective XCD swizzle (gridDim.x % 8 == 0 for all our launches)
  const int cpx = gridDim.x >> 3;
  const int bid = blockIdx.x;
  const int swz = (bid & 7) * cpx + (bid >> 3);
  const int bm = swz / nbn, bn = swz % nbn;
  const int tm = bm * 256, tn = bn * 128;

  // staging source pointers (inverse-swizzled): thread's linear LDS byte X
  // holds global tile byte (row, koff ^ ((row&7)<<4))
  const char* srcA[4];
  const char* srcB[2];
#pragma unroll
  for (int s = 0; s < 4; ++s) {
    int X = (s * 512 + tid) * 16;
    int row = X >> 7;
    int koff = (X & 127) ^ ((row & 7) << 4);
    srcA[s] = (const char*)A + ((size_t)(tm + row) * K) * 2 + koff;
  }
#pragma unroll
  for (int s = 0; s < 2; ++s) {
    int X = (s * 512 + tid) * 16;
    int row = X >> 7;
    int koff = (X & 127) ^ ((row & 7) << 4);
    srcB[s] = (const char*)Bm + ((size_t)(tn + row) * K) * 2 + koff;
  }

  // fragment byte offsets (swizzled reads), fully unrolled indexing
  int offA[4][2], offB[4][2];
#pragma unroll
  for (int m = 0; m < 4; ++m) {
    int row = wrm * 64 + m * 16 + lr;
#pragma unroll
    for (int kk = 0; kk < 2; ++kk)
      offA[m][kk] = row * 128 + ((kk * 64 + c4 * 16) ^ ((row & 7) << 4));
  }
#pragma unroll
  for (int n = 0; n < 4; ++n) {
    int row = wnn * 64 + n * 16 + lr;
#pragma unroll
    for (int kk = 0; kk < 2; ++kk)
      offB[n][kk] = row * 128 + ((kk * 64 + c4 * 16) ^ ((row & 7) << 4));
  }

  auto issueA = [&](int jj, int buf) {
#pragma unroll
    for (int s = 0; s < 4; ++s)
      __builtin_amdgcn_global_load_lds(
          (const __attribute__((address_space(1))) void*)(srcA[s] + (size_t)jj * 128),
          (__attribute__((address_space(3))) void*)(&lds[buf][s * 4096 + w * 512]),
          16, 0, 0);
  };
  auto issueB = [&](int jj, int buf) {
#pragma unroll
    for (int s = 0; s < 2; ++s)
      __builtin_amdgcn_global_load_lds(
          (const __attribute__((address_space(1))) void*)(srcB[s] + (size_t)jj * 128),
          (__attribute__((address_space(3))) void*)(&lds[buf][16384 + s * 4096 + w * 512]),
          16, 0, 0);
  };

  f32x4 acc[4][4] = {};

  // prologue: tiles 0 and 1 in flight (12 loads)
  issueA(0, 0); issueB(0, 0);
  if (NT > 1) { issueA(1, 1); issueB(1, 1); }

  int cur = 0;
  for (int j = 0; j < NT; ++j) {
    // boundary: wait tile j's 6 loads (oldest); tile j+1's 6 stay in flight
    if (j == NT - 1) asm volatile("s_waitcnt vmcnt(0)" ::: "memory");
    else             asm volatile("s_waitcnt vmcnt(6)" ::: "memory");
    __builtin_amdgcn_s_barrier();
    int pf = cur + 2; if (pf >= 3) pf -= 3;
    const char* aB = (const char*)&lds[cur][0];
    const char* bB = (const char*)&lds[cur][16384];

    // ---- phase 0 (kk = 0) ----
    if (j + 2 < NT) issueA(j + 2, pf);
    bf16x8 af[4], bfv[4];
#pragma unroll
    for (int m = 0; m < 4; ++m) af[m]  = *(const bf16x8*)(aB + offA[m][0]);
#pragma unroll
    for (int n = 0; n < 4; ++n) bfv[n] = *(const bf16x8*)(bB + offB[n][0]);
    __builtin_amdgcn_s_barrier();
    __builtin_amdgcn_s_setprio(1);
#pragma unroll
    for (int m = 0; m < 4; ++m)
#pragma unroll
      for (int n = 0; n < 4; ++n)
        acc[m][n] = __builtin_amdgcn_mfma_f32_16x16x32_bf16(af[m], bfv[n], acc[m][n], 0, 0, 0);
    __builtin_amdgcn_s_setprio(0);

    // ---- phase 1 (kk = 1) ----
    if (j + 2 < NT) issueB(j + 2, pf);
#pragma unroll
    for (int m = 0; m < 4; ++m) af[m]  = *(const bf16x8*)(aB + offA[m][1]);
#pragma unroll
    for (int n = 0; n < 4; ++n) bfv[n] = *(const bf16x8*)(bB + offB[n][1]);
    __builtin_amdgcn_s_barrier();
    __builtin_amdgcn_s_setprio(1);
#pragma unroll
    for (int m = 0; m < 4; ++m)
#pragma unroll
      for (int n = 0; n < 4; ++n)
        acc[m][n] = __builtin_amdgcn_mfma_f32_16x16x32_bf16(af[m], bfv[n], acc[m][n], 0, 0, 0);
    __builtin_amdgcn_s_setprio(0);

    cur = cur + 1; if (cur >= 3) cur = 0;
  }

  // epilogue
#pragma unroll
  for (int m = 0; m < 4; ++m)
#pragma unroll
    for (int n = 0; n < 4; ++n)
#pragma unroll
      for (int r = 0; r < 4; ++r) {
        size_t idx = (size_t)(tm + wrm * 64 + m * 16 + c4 * 4 + r) * N
                   + (tn + wnn * 64 + n * 16 + lr);
        if (BF16OUT) ((short*)Cv)[idx] = f2bf(acc[m][n][r]);
        else         ((float*)Cv)[idx] = acc[m][n][r];
      }
}

// ---------------- RoPE + pack Q (scaled) and K to [B,H,L,DH] bf16 ----------------
__global__ __launch_bounds__(256) void rope_pack_kernel(
    const short* __restrict__ qkv, const float* __restrict__ cost,
    const float* __restrict__ sint, short* __restrict__ Qp,
    short* __restrict__ Kp) {
  int idx = blockIdx.x * 256 + threadIdx.x;   // B*L*H*64 = 4194304
  int dh = idx & 63;
  int h  = (idx >> 6) & 15;
  int l  = (idx >> 10) & 2047;
  int b  = idx >> 21;
  size_t src = (size_t)(b * L_ + l) * (3 * D_);
  int e = h * DH_ + dh;
  float c = cost[l * 64 + dh], s = sint[l * 64 + dh];
  float q1 = bf2f(qkv[src + e]),        q2 = bf2f(qkv[src + e + 64]);
  float k1 = bf2f(qkv[src + D_ + e]),   k2 = bf2f(qkv[src + D_ + e + 64]);
  const float scale = 0.08838834764831845f;   // 1/sqrt(128), folded into Q
  size_t dst = ((size_t)(b * H_ + h) * L_ + l) * DH_ + dh;
  Qp[dst]      = f2bf((q1 * c - q2 * s) * scale);
  Qp[dst + 64] = f2bf((q2 * c + q1 * s) * scale);
  Kp[dst]      = f2bf(k1 * c - k2 * s);
  Kp[dst + 64] = f2bf(k2 * c + k1 * s);
}

// ---------------- V transpose: qkv V-part [b,l,h,d] -> VtG [b,h,d,l] ----------------
// diagonal-LDS 64x64 tile transpose (conflict-free scalar writes/reads)
__global__ __launch_bounds__(256) void transpose_v_kernel(
    const short* __restrict__ qkv, short* __restrict__ VtG) {
  __shared__ short T[64 * 64];
  int bid = blockIdx.x;              // 32(lt) x 2(dt) x 32(bh) = 2048
  int lt = bid & 31, dt = (bid >> 5) & 1, bh = bid >> 6;
  int b = bh >> 4, h = bh & 15;
  int l0 = lt * 64, d0 = dt * 64;
  int tid = threadIdx.x;
#pragma unroll
  for (int it = 0; it < 2; ++it) {
    int row = it * 32 + (tid >> 3);      // local l
    int c   = (tid & 7) * 8;             // local d chunk
    bf16x8 v = *(const bf16x8*)&qkv[(size_t)(b * L_ + l0 + row) * (3 * D_) + 2 * D_ + h * DH_ + d0 + c];
#pragma unroll
    for (int jj = 0; jj < 8; ++jj)
      T[row * 64 + ((c + jj + row) & 63)] = v[jj];
  }
  __syncthreads();
  int d = tid >> 2, lc = (tid & 3) * 16;
  short tmp[16];
#pragma unroll
  for (int j = 0; j < 16; ++j)
    tmp[j] = T[(lc + j) * 64 + ((d + lc + j) & 63)];
  size_t obase = (size_t)(bh * DH_ + d0 + d) * L_ + l0 + lc;
  *(bf16x8*)&VtG[obase]     = *(bf16x8*)&tmp[0];
  *(bf16x8*)&VtG[obase + 8] = *(bf16x8*)&tmp[8];
}

// ---------------- causal flash attention ----------------
// 512 blocks (XCD-grouped), 4 waves x 32 q-rows = 128 q/block, KVBLK=64.
// 32x32x16 MFMA, swapped QK^T (S^T), in-register P exchange, dbuf staging.
__global__ __launch_bounds__(256) void attn_kernel(
    const short* __restrict__ Qp, const short* __restrict__ Kp,
    const short* __restrict__ VtG, short* __restrict__ Out) {
  __shared__ short lds[2][16384];    // per buf: K 64x128 (8192) + Vt 128x64 (8192), XOR-swizzled

  const int f   = blockIdx.x;        // 0..511
  const int bh  = (f & 7) + 8 * (f >> 7);
  const int qt  = (f >> 3) & 15;
  const int q0  = qt * 128;
  const int tid = threadIdx.x;
  const int w = tid >> 6, l = tid & 63;
  const int lq = l & 31, hi = l >> 5;
  const int qw = q0 + w * 32;
  const int b = bh >> 4, h = bh & 15;
  const size_t kqbase = (size_t)bh * (L_ * DH_);

  // Q fragments (B-operand of swapped QK^T): lane owns q = qw+lq, all 128 d
  bf16x8 qf[8];
#pragma unroll
  for (int st = 0; st < 8; ++st)
    qf[st] = *(const bf16x8*)&Qp[kqbase + (size_t)(qw + lq) * DH_ + st * 16 + hi * 8];

  f32x16 oacc[4];
#pragma unroll
  for (int dm = 0; dm < 4; ++dm)
#pragma unroll
    for (int r = 0; r < 16; ++r) oacc[dm][r] = 0.f;
  float m_run = -1e30f, l_run = 0.f;

  const int nt = qt * 2 + 2;

  auto stage = [&](int bf, int kt) {
    int k0 = kt * 64;
#pragma unroll
    for (int i = 0; i < 4; ++i) {
      int c = w * 4 + i;
      int X = c * 1024 + l * 16;
      {  // K region: 64 rows x 256 B, row-bit XOR swizzled source
        int row = X >> 8, bcol = (X & 255) ^ ((row & 7) << 4);
        __builtin_amdgcn_global_load_lds(
            (const __attribute__((address_space(1))) void*)(Kp + kqbase + (size_t)(k0 + row) * DH_ + (bcol >> 1)),
            (__attribute__((address_space(3))) void*)(&lds[bf][c * 512]), 16, 0, 0);
      }
      {  // Vt region: 128 rows x 128 B
        int row = X >> 7, bcol = (X & 127) ^ ((row & 7) << 4);
        __builtin_amdgcn_global_load_lds(
            (const __attribute__((address_space(1))) void*)(VtG + (size_t)(bh * DH_ + row) * L_ + k0 + (bcol >> 1)),
            (__attribute__((address_space(3))) void*)(&lds[bf][8192 + c * 512]), 16, 0, 0);
      }
    }
  };

  auto compute = [&](int bf, int kt) {
    int k0 = kt * 64;
    if (k0 > qw + 31) return;          // wave fully above diagonal: skip
    const char* ksB = (const char*)&lds[bf][0];
    const char* vsB = (const char*)&lds[bf][8192];

    // S^T = K . Q^T   (2 frags of 32k x 32q, contraction over d=128)
    f32x16 sacc[2];
#pragma unroll
    for (int fm = 0; fm < 2; ++fm)
#pragma unroll
      for (int r = 0; r < 16; ++r) sacc[fm][r] = 0.f;
#pragma unroll
    for (int st = 0; st < 8; ++st) {
#pragma unroll
      for (int fm = 0; fm < 2; ++fm) {
        int krow = fm * 32 + lq;
        int byte = (krow << 8) + ((st * 32 + hi * 16) ^ ((krow & 7) << 4));
        bf16x8 kf = *(const bf16x8*)(ksB + byte);
        sacc[fm] = __builtin_amdgcn_mfma_f32_32x32x16_bf16(kf, qf[st], sacc[fm], 0, 0, 0);
      }
    }

    // causal mask (only on diagonal-crossing tiles; k = k0+fm*32+(r&3)+8*(r>>2)+4*hi, q = qw+lq)
    if (k0 + 63 > qw) {
      int q = qw + lq;
#pragma unroll
      for (int fm = 0; fm < 2; ++fm)
#pragma unroll
        for (int r = 0; r < 16; ++r) {
          int k = k0 + fm * 32 + (r & 3) + 8 * (r >> 2) + 4 * hi;
          if (k > q) sacc[fm][r] = -1e30f;
        }
    }

    // online softmax: lane-local over 32 k + combine with partner lane (l^32, same q)
    float pmax = sacc[0][0];
#pragma unroll
    for (int fm = 0; fm < 2; ++fm)
#pragma unroll
      for (int r = 0; r < 16; ++r) pmax = fmaxf(pmax, sacc[fm][r]);
    pmax = fmaxf(pmax, __shfl_xor(pmax, 32));
    float mnew = fmaxf(m_run, pmax);
    float alpha = __expf(m_run - mnew);
    m_run = mnew;
    float rsum = 0.f;
#pragma unroll
    for (int fm = 0; fm < 2; ++fm)
#pragma unroll
      for (int r = 0; r < 16; ++r) {
        float e = __expf(sacc[fm][r] - mnew);
        sacc[fm][r] = e;
        rsum += e;
      }
    rsum += __shfl_xor(rsum, 32);
    l_run = l_run * alpha + rsum;
#pragma unroll
    for (int dm = 0; dm < 4; ++dm)
#pragma unroll
      for (int r = 0; r < 16; ++r) oacc[dm][r] *= alpha;

    // P -> bf16 packed dwords (pb[fm*8+i] = {p[2i], p[2i+1]})
    int pb[16];
#pragma unroll
    for (int fm = 0; fm < 2; ++fm)
#pragma unroll
      for (int i2 = 0; i2 < 8; ++i2)
        pb[fm * 8 + i2] = pkbf(sacc[fm][2 * i2], sacc[fm][2 * i2 + 1]);

    // O^T += V^T . P^T : per 16-k slice, build P-frag via shfl_xor(32)+select
#pragma unroll
    for (int kk = 0; kk < 4; ++kk) {
      int idx0 = (kk >> 1) * 8 + (kk & 1) * 4;
      int sw0 = __shfl_xor(pb[idx0],     32);
      int sw1 = __shfl_xor(pb[idx0 + 1], 32);
      int sw2 = __shfl_xor(pb[idx0 + 2], 32);
      int sw3 = __shfl_xor(pb[idx0 + 3], 32);
      union { int i[4]; bf16x8 v; } u;
      u.i[0] = hi ? sw2 : pb[idx0];
      u.i[1] = hi ? sw3 : pb[idx0 + 1];
      u.i[2] = hi ? pb[idx0 + 2] : sw0;
      u.i[3] = hi ? pb[idx0 + 3] : sw1;
#pragma unroll
      for (int dm = 0; dm < 4; ++dm) {
        int vrow = dm * 32 + lq;
        int byte = (vrow << 7) + ((kk * 32 + hi * 16) ^ ((vrow & 7) << 4));
        bf16x8 vf = *(const bf16x8*)(vsB + byte);
        oacc[dm] = __builtin_amdgcn_mfma_f32_32x32x16_bf16(vf, u.v, oacc[dm], 0, 0, 0);
      }
    }
  };

  stage(0, 0);
  __syncthreads();
  for (int kt = 0; kt < nt; ++kt) {
    if (kt + 1 < nt) stage((kt + 1) & 1, kt + 1);
    compute(kt & 1, kt);
    __syncthreads();
  }

  // epilogue: O^T[d][q] / l_run -> Out[b, q, h*128+d] bf16
  float inv = 1.0f / l_run;
  int q = qw + lq;
  size_t rowbase = ((size_t)(b * L_ + q)) * D_ + h * DH_;
#pragma unroll
  for (int dm = 0; dm < 4; ++dm)
#pragma unroll
    for (int g = 0; g < 4; ++g) {
      short4v s4;
#pragma unroll
      for (int t = 0; t < 4; ++t) s4[t] = f2bf(oacc[dm][4 * g + t] * inv);
      *(short4v*)&Out[rowbase + dm * 32 + 8 * g + 4 * hi] = s4;
    }
}

// ---------------- launcher ----------------
extern "C" void kernel_launch(void* const* d_in, const int* in_sizes, int n_in,
                              void* d_out, int out_size, void* d_ws, size_t ws_size,
                              hipStream_t stream) {
  const float* x     = (const float*)d_in[0];
  const float* w_qkv = (const float*)d_in[1];
  const float* w_out = (const float*)d_in[2];
  float* out = (float*)d_out;

  char* ws = (char*)d_ws;
  size_t off = 0;
  auto alloc = [&](size_t bytes) -> char* {
    char* p = ws + off;
    off += (bytes + 255) & ~(size_t)255;
    return p;
  };
  const size_t nX = (size_t)B_ * L_ * D_;          // 8388608
  const size_t nWqkv = (size_t)3 * D_ * D_;        // 12582912
  const size_t nWout = (size_t)D_ * D_;            // 4194304
  short* xb    = (short*)alloc(nX * 2);
  short* wqkvb = (short*)alloc(nWqkv * 2);
  short* woutb = (short*)alloc(nWout * 2);
  short* qkvb  = (short*)alloc((size_t)B_ * L_ * 3 * D_ * 2);
  short* Qp    = (short*)alloc(nX * 2);
  short* Kp    = (short*)alloc(nX * 2);
  short* VtG   = (short*)alloc(nX * 2);
  short* attnb = (short*)alloc(nX * 2);
  float* cost  = (float*)alloc((size_t)L_ * 64 * 4);
  float* sint  = (float*)alloc((size_t)L_ * 64 * 4);

  // 1. convert inputs to bf16
  cvt_bf16_kernel<<<(int)(nX / 1024), 256, 0, stream>>>(x, xb, (int)(nX / 4));
  cvt_bf16_kernel<<<(int)(nWqkv / 1024), 256, 0, stream>>>(w_qkv, wqkvb, (int)(nWqkv / 4));
  cvt_bf16_kernel<<<(int)(nWout / 1024), 256, 0, stream>>>(w_out, woutb, (int)(nWout / 4));
  // 2. rope tables
  rope_table_kernel<<<(L_ * 64) / 256, 256, 0, stream>>>(cost, sint);
  // 3. qkv = x @ w_qkv^T   [4096, 6144] bf16   (768 blocks = 3.0 rounds)
  gemm256_kernel<true><<<768, 512, 0, stream>>>(xb, wqkvb, (void*)qkvb,
                                                B_ * L_, 3 * D_, D_, 48);
  // 4. rope + pack Q,K ; transpose V
  rope_pack_kernel<<<(int)(nX / 512), 256, 0, stream>>>(qkvb, cost, sint, Qp, Kp);
  transpose_v_kernel<<<2048, 256, 0, stream>>>(qkvb, VtG);
  // 5. attention
  attn_kernel<<<512, 256, 0, stream>>>(Qp, Kp, VtG, attnb);
  // 6. out = attn @ w_out^T  [4096, 2048] fp32   (256 blocks = 1.0 round)
  gemm256_kernel<false><<<256, 512, 0, stream>>>(attnb, woutb, (void*)out,
                                                 B_ * L_, D_, D_, 16);
}